// Round 5
// baseline (63.506 us; speedup 1.0000x reference)
//
#include <hip/hip_runtime.h>
#include <stdint.h>

#define NB 2048
#define NCLASSES 80
#define CONF_T 0.05f
#define IOU_T 0.5f
#define MAX_DET 100
#define MAX_PER_CLASS 100
#define ECAP 2048

typedef unsigned long long u64;
typedef unsigned int u32;

__device__ __forceinline__ u64 shfl_xor_u64(u64 v, int mask) {
    int lo = (int)(u32)v, hi = (int)(u32)(v >> 32);
    lo = __shfl_xor(lo, mask, 64);
    hi = __shfl_xor(hi, mask, 64);
    return ((u64)(u32)hi << 32) | (u32)lo;
}

// ====================================================================
// Fused per-batch NMS: sort + class-bucketed pair tests + greedy
// resolve + cap + compacted output, all in one block (1024 thr).
// ====================================================================
__global__ __launch_bounds__(1024) void nms_fused(const float* __restrict__ pred,
                                                  float* __restrict__ out, int B) {
    const int b = blockIdx.x, tid = threadIdx.x;
    const int lane = tid & 63, wave = tid >> 6;

    __shared__ u64 keys[NB];                   // 16 KB
    __shared__ short kcls[NB];                 // 4 KB  (keep ? cls : -1)
    __shared__ unsigned short clsList[NB];     // 4 KB  (sorted-idx bucketed by class)
    __shared__ int clsCnt[NCLASSES], clsOff[NCLASSES], clsFill[NCLASSES];
    __shared__ u32 se[ECAP];                   // 8 KB  (suppression edges)
    __shared__ u64 kept[32];
    __shared__ int kcnt[32], kbase[32];
    __shared__ int eCnt, ovf;

    const float* P = pred + (size_t)b * NB * 6;

    if (tid < NCLASSES) { clsCnt[tid] = 0; clsFill[tid] = 0; }
    if (tid == 0) { eCnt = 0; ovf = 0; }

    // ---- Phase 1: hybrid bitonic sort (validated round-4 structure) ----
    const int base = wave * 128;
    const int iA = base + lane, iB = base + 64 + lane;

    float sA = P[iA * 6 + 5];
    float sB = P[iB * 6 + 5];
    u64 A = (sA > CONF_T) ? (((u64)__float_as_uint(sA) << 32) | (u32)iA) : (u64)(u32)iA;
    u64 Bk = (sB > CONF_T) ? (((u64)__float_as_uint(sB) << 32) | (u32)iB) : (u64)(u32)iB;

    auto phase_local = [&](int k) {
        bool up = ((iA & k) == 0);
        u64 mx = A > Bk ? A : Bk, mn = A > Bk ? Bk : A;
        A = up ? mx : mn;
        Bk = up ? mn : mx;
    };
    auto phase_shfl = [&](int j, int k) {
        u64 pA = shfl_xor_u64(A, j);
        u64 pB = shfl_xor_u64(Bk, j);
        bool low = ((lane & j) == 0);
        bool upA = ((iA & k) == 0);
        bool upB = ((iB & k) == 0);
        A  = (low == upA) ? (A  > pA ? A  : pA) : (A  > pA ? pA : A);
        Bk = (low == upB) ? (Bk > pB ? Bk : pB) : (Bk > pB ? pB : Bk);
    };

    for (int k = 2; k <= 128; k <<= 1) {
        if (k == 128) phase_local(k);
        for (int j = (k == 128 ? 32 : (k >> 1)); j >= 1; j >>= 1) phase_shfl(j, k);
    }
    keys[iA] = A; keys[iB] = Bk;
    __syncthreads();

    for (int k = 256; k <= NB; k <<= 1) {
        for (int j = k >> 1; j >= 128; j >>= 1) {
            const int i1 = ((tid & ~(j - 1)) << 1) | (tid & (j - 1));
            const int i2 = i1 + j;
            const bool up = ((i1 & k) == 0);
            u64 a = keys[i1], c = keys[i2];
            if (up ? (a < c) : (a > c)) { keys[i1] = c; keys[i2] = a; }
            __syncthreads();
        }
        A = keys[iA]; Bk = keys[iB];
        phase_local(k);
        for (int j = 32; j >= 1; j >>= 1) phase_shfl(j, k);
        keys[iA] = A; keys[iB] = Bk;
        __syncthreads();
    }

    // ---- Phase 2: gather classes + per-class counts ----
    for (int i = tid; i < NB; i += 1024) {
        u64 k = keys[i];
        int c = -1;
        if (k >> 32) {
            int orig = (int)(u32)k;
            c = (int)P[orig * 6 + 4];
            atomicAdd(&clsCnt[c], 1);
        }
        kcls[i] = (short)c;
    }
    __syncthreads();
    if (tid == 0) {
        int s = 0;
        for (int c = 0; c < NCLASSES; ++c) {
            clsOff[c] = s; s += clsCnt[c];
            if (clsCnt[c] > MAX_PER_CLASS) ovf = 1;
        }
    }
    __syncthreads();
    for (int i = tid; i < NB; i += 1024) {
        int c = kcls[i];
        if (c >= 0) {
            int p = clsOff[c] + atomicAdd(&clsFill[c], 1);
            clsList[p] = (unsigned short)i;
        }
    }
    __syncthreads();

    // ---- Phase 3: intra-class pair tests (wave w owns classes w, w+16, ...) ----
    for (int c = wave; c < NCLASSES; c += 16) {
        int off = clsOff[c], cnt = clsCnt[c];
        if (cnt < 2) continue;
        if (cnt <= 64) {
            int si = -1;
            float x1 = 0.f, y1 = 0.f, x2 = 0.f, y2 = 0.f, ar = 0.f;
            if (lane < cnt) {
                si = clsList[off + lane];
                int orig = (int)(u32)keys[si];
                const float* q = P + orig * 6;
                x1 = q[0]; y1 = q[1]; x2 = q[2]; y2 = q[3];
                ar = fmaxf(x2 - x1, 0.f) * fmaxf(y2 - y1, 0.f);
            }
            for (int a = 0; a + 1 < cnt; ++a) {
                int sa = __shfl(si, a, 64);
                float ax1 = __shfl(x1, a, 64), ay1 = __shfl(y1, a, 64);
                float ax2 = __shfl(x2, a, 64), ay2 = __shfl(y2, a, 64);
                float aar = __shfl(ar, a, 64);
                if (lane > a && lane < cnt) {
                    float ix1 = fmaxf(ax1, x1), iy1 = fmaxf(ay1, y1);
                    float ix2 = fminf(ax2, x2), iy2 = fminf(ay2, y2);
                    float inter = fmaxf(ix2 - ix1, 0.f) * fmaxf(iy2 - iy1, 0.f);
                    float uni = aar + ar - inter;
                    if (inter / fmaxf(uni, 1e-8f) > IOU_T) {
                        int i1 = sa < si ? sa : si, j1 = sa < si ? si : sa;
                        int e = atomicAdd(&eCnt, 1);
                        if (e < ECAP) se[e] = ((u32)i1 << 11) | (u32)j1;
                    }
                }
            }
        } else {
            // exact fallback for cnt > 64 (statistically never taken)
            for (int a = 0; a + 1 < cnt; ++a) {
                int sa = clsList[off + a];
                int origa = (int)(u32)keys[sa];
                const float* qa = P + origa * 6;
                float ax1 = qa[0], ay1 = qa[1], ax2 = qa[2], ay2 = qa[3];
                float aar = fmaxf(ax2 - ax1, 0.f) * fmaxf(ay2 - ay1, 0.f);
                for (int bp = a + 1 + lane; bp < cnt; bp += 64) {
                    int sb = clsList[off + bp];
                    int origb = (int)(u32)keys[sb];
                    const float* qb = P + origb * 6;
                    float bx1 = qb[0], by1 = qb[1], bx2 = qb[2], by2 = qb[3];
                    float br = fmaxf(bx2 - bx1, 0.f) * fmaxf(by2 - by1, 0.f);
                    float ix1 = fmaxf(ax1, bx1), iy1 = fmaxf(ay1, by1);
                    float ix2 = fminf(ax2, bx2), iy2 = fminf(ay2, by2);
                    float inter = fmaxf(ix2 - ix1, 0.f) * fmaxf(iy2 - iy1, 0.f);
                    float uni = aar + br - inter;
                    if (inter / fmaxf(uni, 1e-8f) > IOU_T) {
                        int i1 = sa < sb ? sa : sb, j1 = sa < sb ? sb : sa;
                        int e = atomicAdd(&eCnt, 1);
                        if (e < ECAP) se[e] = ((u32)i1 << 11) | (u32)j1;
                    }
                }
            }
        }
    }
    // build kept bitmask (independent of edge list)
    for (int cc = wave; cc < 32; cc += 16) {
        u64 m = __ballot(kcls[cc * 64 + lane] >= 0);
        if (lane == 0) kept[cc] = m;
    }
    __syncthreads();

    int E = eCnt; if (E > ECAP) E = ECAP;

    // ---- Phase 4: sort edges ascending (determinism) ----
    if (E > 1) {
        if (E <= 64) {
            if (wave == 0) {
                u32 v = (lane < E) ? se[lane] : 0xFFFFFFFFu;
                for (int k = 2; k <= 64; k <<= 1)
                    for (int j = k >> 1; j >= 1; j >>= 1) {
                        u32 p = (u32)__shfl((int)v, lane ^ j, 64);
                        bool low = (lane & j) == 0;
                        bool up = (lane & k) == 0;
                        v = (low == up) ? (v < p ? v : p) : (v > p ? v : p);
                    }
                if (lane < E) se[lane] = v;
            }
            __syncthreads();
        } else {
            int M = 64; while (M < E) M <<= 1;
            for (int e = tid; e < M; e += 1024) if (e >= E) se[e] = 0xFFFFFFFFu;
            __syncthreads();
            for (int k = 2; k <= M; k <<= 1)
                for (int j = k >> 1; j > 0; j >>= 1) {
                    for (int p = tid; p < (M >> 1); p += 1024) {
                        int i1 = ((p & ~(j - 1)) << 1) | (p & (j - 1));
                        int i2 = i1 + j;
                        u32 a = se[i1], c2 = se[i2];
                        bool up = ((i1 & k) == 0);
                        if (up ? (a > c2) : (a < c2)) { se[i1] = c2; se[i2] = a; }
                    }
                    __syncthreads();
                }
        }
    }

    // ---- Phase 5: greedy resolve (sources ascending = greedy order) ----
    if (tid == 0) {
        for (int e = 0; e < E; ++e) {
            u32 v = se[e];
            int i = v >> 11, j = v & 2047;
            if ((kept[i >> 6] >> (i & 63)) & 1ull)
                kept[j >> 6] &= ~(1ull << (j & 63));
        }
    }
    __syncthreads();

    // ---- Phase 6: per-class cap. Valid counts <=100 => kept rank <=100.
    if (ovf) {               // uniform; exact fallback, ~never taken
        if (tid == 0) {
            for (int c = 0; c < NCLASSES; ++c) clsFill[c] = 0;
            for (int i = 0; i < NB; ++i) {
                int c = kcls[i];
                if (c >= 0 && ((kept[i >> 6] >> (i & 63)) & 1ull))
                    if (++clsFill[c] > MAX_PER_CLASS)
                        kept[i >> 6] &= ~(1ull << (i & 63));
            }
        }
        __syncthreads();
    }

    // ---- Phase 7: compaction + output ----
    for (int cc = wave; cc < 32; cc += 16)
        if (lane == 0) kcnt[cc] = __popcll(kept[cc]);
    __syncthreads();
    if (tid < 32) {
        int s = 0;
        for (int c = 0; c < tid; ++c) s += kcnt[c];
        kbase[tid] = s;
    }
    __syncthreads();

    float* boxes_out   = out + (size_t)b * MAX_DET * 4;
    float* scores_out  = out + (size_t)B * MAX_DET * 4 + (size_t)b * MAX_DET;
    float* classes_out = out + (size_t)B * MAX_DET * 5 + (size_t)b * MAX_DET;
    float* numdet_out  = out + (size_t)B * MAX_DET * 6 + b;

    for (int cc = wave; cc < 32; cc += 16) {
        u64 m = kept[cc];
        int j = cc * 64 + lane;
        bool kp = (m >> lane) & 1ull;
        int pos = kbase[cc] + __popcll(m & ((1ull << lane) - 1ull));
        if (kp && pos < MAX_DET) {
            int orig = (int)(u32)keys[j];
            const float* q = P + orig * 6;
            boxes_out[pos * 4 + 0] = q[0];
            boxes_out[pos * 4 + 1] = q[1];
            boxes_out[pos * 4 + 2] = q[2];
            boxes_out[pos * 4 + 3] = q[3];
            scores_out[pos]  = __uint_as_float((u32)(keys[j] >> 32));
            classes_out[pos] = (float)kcls[j];
        }
    }
    int total = kbase[31] + kcnt[31];
    int nd = total < MAX_DET ? total : MAX_DET;
    for (int p = nd + tid; p < MAX_DET; p += 1024) {
        boxes_out[p * 4 + 0] = 0.f;
        boxes_out[p * 4 + 1] = 0.f;
        boxes_out[p * 4 + 2] = 0.f;
        boxes_out[p * 4 + 3] = 0.f;
        scores_out[p]  = 0.f;
        classes_out[p] = 0.f;
    }
    if (tid == 0) *numdet_out = (float)nd;
}

extern "C" void kernel_launch(void* const* d_in, const int* in_sizes, int n_in,
                              void* d_out, int out_size, void* d_ws, size_t ws_size,
                              hipStream_t stream) {
    const float* pred = (const float*)d_in[0];
    float* out = (float*)d_out;
    const int B = in_sizes[0] / (NB * 6);
    nms_fused<<<B, 1024, 0, stream>>>(pred, out, B);
}

// Round 6
// 38.910 us; speedup vs baseline: 1.6321x; 1.6321x over previous
//
#include <hip/hip_runtime.h>
#include <stdint.h>

#define NB 2048
#define NCLASSES 80
#define CONF_T 0.05f
#define IOU_T 0.5f
#define MAX_DET 100
#define MAX_PER_CLASS 100

typedef unsigned long long u64;
typedef unsigned int u32;

__device__ __forceinline__ u64 shfl_xor_u64(u64 v, int mask) {
    int lo = (int)(u32)v, hi = (int)(u32)(v >> 32);
    lo = __shfl_xor(lo, mask, 64);
    hi = __shfl_xor(hi, mask, 64);
    return ((u64)(u32)hi << 32) | (u32)lo;
}

// ====================================================================
// K1 (512 thr/batch): hybrid bitonic sort, 4 elems/thread (wave owns a
// 256-elem segment; k<=256 rounds fully register-resident; only j>=256
// phases via LDS => 10 barriers at 8 waves). Then class-bucket the
// sorted keys (LDS counts -> wave-parallel shfl prefix -> scatter).
// ====================================================================
__global__ __launch_bounds__(512) void k1_sort(const float* __restrict__ pred,
                                               u64* __restrict__ keysG,
                                               u64* __restrict__ keyBuck,
                                               int* __restrict__ clsOffG,
                                               int* __restrict__ clsCntG,
                                               int* __restrict__ supCnt) {
    const int b = blockIdx.x, tid = threadIdx.x;
    const int lane = tid & 63, wave = tid >> 6;          // 8 waves
    __shared__ u64 keys[NB];                             // 16 KB
    __shared__ short kcls[NB];                           // 4 KB
    __shared__ int clsCnt[NCLASSES], clsOff[NCLASSES], clsFill[NCLASSES];
    const float* P = pred + (size_t)b * NB * 6;

    if (tid < NCLASSES) { clsCnt[tid] = 0; clsFill[tid] = 0; }
    if (tid == 0) supCnt[b] = 0;

    const int sbase = wave * 256;
    const int iA = sbase + lane, iB = iA + 64, iC = iA + 128, iD = iA + 192;

    auto mkkey = [&](int i) -> u64 {
        float s = P[i * 6 + 5];
        return (s > CONF_T) ? (((u64)__float_as_uint(s) << 32) | (u32)i)
                            : (u64)(u32)i;
    };
    u64 A = mkkey(iA), B = mkkey(iB), C = mkkey(iC), D = mkkey(iD);

    auto loc = [&](u64& X, u64& Y, int ix, int k) {      // pair (ix, ix+dist)
        bool up = ((ix & k) == 0);
        u64 mx = X > Y ? X : Y, mn = X > Y ? Y : X;
        X = up ? mx : mn; Y = up ? mn : mx;
    };
    auto shf = [&](u64& V, int iv, int j, int k) {
        u64 p = shfl_xor_u64(V, j);
        bool low = ((lane & j) == 0);
        bool up  = ((iv & k) == 0);
        V = (low == up) ? (V > p ? V : p) : (V < p ? V : p);
    };
    auto tail = [&](int k, int jstart) {
        if (jstart >= 128) { loc(A, C, iA, k); loc(B, D, iB, k); }
        if (jstart >= 64)  { loc(A, B, iA, k); loc(C, D, iC, k); }
        for (int j = (jstart > 32 ? 32 : jstart); j >= 1; j >>= 1) {
            shf(A, iA, j, k); shf(B, iB, j, k); shf(C, iC, j, k); shf(D, iD, j, k);
        }
    };

    for (int k = 2; k <= 256; k <<= 1) tail(k, k >> 1);
    keys[iA] = A; keys[iB] = B; keys[iC] = C; keys[iD] = D;
    __syncthreads();

    for (int k = 512; k <= NB; k <<= 1) {
        for (int j = k >> 1; j >= 256; j >>= 1) {
            for (int pp = tid; pp < (NB >> 1); pp += 512) {
                int i1 = ((pp & ~(j - 1)) << 1) | (pp & (j - 1));
                int i2 = i1 + j;
                bool up = ((i1 & k) == 0);
                u64 a = keys[i1], c = keys[i2];
                if (up ? (a < c) : (a > c)) { keys[i1] = c; keys[i2] = a; }
            }
            __syncthreads();
        }
        A = keys[iA]; B = keys[iB]; C = keys[iC]; D = keys[iD];
        tail(k, 128);
        keys[iA] = A; keys[iB] = B; keys[iC] = C; keys[iD] = D;
        __syncthreads();
    }

    // ---- class pass: classes + counts ----
    for (int i = tid; i < NB; i += 512) {
        u64 k = keys[i];
        int c = -1;
        if (k >> 32) { c = (int)P[(int)(u32)k * 6 + 4]; atomicAdd(&clsCnt[c], 1); }
        kcls[i] = (short)c;
    }
    __syncthreads();
    // ---- wave-parallel exclusive prefix over 80 class counts ----
    if (wave == 0) {
        int v0 = clsCnt[lane];                                   // classes 0..63
        int v1 = (lane < NCLASSES - 64) ? clsCnt[64 + lane] : 0; // classes 64..79
        int s0 = v0;
        #pragma unroll
        for (int d = 1; d < 64; d <<= 1) { int t = __shfl_up(s0, d, 64); if (lane >= d) s0 += t; }
        int tot0 = __shfl(s0, 63, 64);
        int s1 = v1;
        #pragma unroll
        for (int d = 1; d < 16; d <<= 1) { int t = __shfl_up(s1, d, 64); if (lane >= d) s1 += t; }
        clsOff[lane] = s0 - v0;
        if (lane < NCLASSES - 64) clsOff[64 + lane] = tot0 + (s1 - v1);
    }
    __syncthreads();
    // ---- scatter (order within bucket irrelevant; k2 re-sorts) ----
    for (int i = tid; i < NB; i += 512) {
        keysG[(size_t)b * NB + i] = keys[i];
        int c = kcls[i];
        if (c >= 0) {
            int p = clsOff[c] + atomicAdd(&clsFill[c], 1);
            keyBuck[(size_t)b * NB + p] = keys[i];
        }
    }
    if (tid < NCLASSES) {
        clsCntG[b * NCLASSES + tid] = clsCnt[tid];
        clsOffG[b * NCLASSES + tid] = clsOff[tid];
    }
}

// ====================================================================
// K2 (one wave per (class,batch)): in-wave sort class keys descending
// (keys unique => exact global tie-break), in-register greedy NMS,
// append suppressed orig-indices to supList. Exact fallback cnt>64.
// ====================================================================
__global__ __launch_bounds__(64) void k2_nms(const float* __restrict__ pred,
                                             const u64* __restrict__ keyBuck,
                                             const int* __restrict__ clsOffG,
                                             const int* __restrict__ clsCntG,
                                             u32* __restrict__ supList,
                                             int* __restrict__ supCnt) {
    const int c = blockIdx.x, b = blockIdx.y, lane = threadIdx.x;
    __shared__ unsigned char fstate[NB];   // fallback only
    const int cnt = clsCntG[b * NCLASSES + c];
    if (cnt < 2) return;
    const int off = clsOffG[b * NCLASSES + c];
    const float* P = pred + (size_t)b * NB * 6;
    const u64* kb = keyBuck + (size_t)b * NB + off;

    if (cnt <= 64) {
        u64 v = (lane < cnt) ? kb[lane] : 0ull;
        for (int k = 2; k <= 64; k <<= 1)
            for (int j = k >> 1; j >= 1; j >>= 1) {
                u64 p = shfl_xor_u64(v, j);
                bool low = (lane & j) == 0, up = (lane & k) == 0;
                v = (low == up) ? (v > p ? v : p) : (v < p ? v : p);
            }
        int orig = (int)(u32)v;
        float x1 = 0.f, y1 = 0.f, x2 = 0.f, y2 = 0.f, ar = 0.f;
        if (lane < cnt) {
            const float* q = P + orig * 6;
            x1 = q[0]; y1 = q[1]; x2 = q[2]; y2 = q[3];
            ar = fmaxf(x2 - x1, 0.f) * fmaxf(y2 - y1, 0.f);
        }
        u64 aliveM = __ballot(lane < cnt);
        for (int a = 0; a + 1 < cnt; ++a) {
            if (!((aliveM >> a) & 1ull)) continue;     // uniform
            float ax1 = __shfl(x1, a, 64), ay1 = __shfl(y1, a, 64);
            float ax2 = __shfl(x2, a, 64), ay2 = __shfl(y2, a, 64);
            float aar = __shfl(ar, a, 64);
            bool kill = false;
            if (lane > a && ((aliveM >> lane) & 1ull)) {
                float ix1 = fmaxf(ax1, x1), iy1 = fmaxf(ay1, y1);
                float ix2 = fminf(ax2, x2), iy2 = fminf(ay2, y2);
                float inter = fmaxf(ix2 - ix1, 0.f) * fmaxf(iy2 - iy1, 0.f);
                float uni = aar + ar - inter;
                kill = inter / fmaxf(uni, 1e-8f) > IOU_T;
            }
            aliveM &= ~__ballot(kill);
        }
        if (lane < cnt && !((aliveM >> lane) & 1ull)) {
            int p = atomicAdd(&supCnt[b], 1);
            supList[(size_t)b * NB + p] = (u32)orig;
        }
    } else {
        // ---- exact slow fallback (statistically never taken) ----
        for (int e = lane; e < cnt; e += 64) fstate[e] = 0;
        __syncthreads();
        int keptCount = 0;
        for (;;) {
            u64 best = 0ull; int bi = -1;
            for (int e = lane; e < cnt; e += 64)
                if (fstate[e] == 0) { u64 kv = kb[e]; if (kv > best) { best = kv; bi = e; } }
            for (int d = 32; d >= 1; d >>= 1) {
                u64 ob = shfl_xor_u64(best, d);
                int obi = __shfl_xor(bi, d, 64);
                if (ob > best) { best = ob; bi = obi; }
            }
            if (best == 0ull) break;
            keptCount++;
            int orig = (int)(u32)best;
            const float* q = P + orig * 6;
            float ax1 = q[0], ay1 = q[1], ax2 = q[2], ay2 = q[3];
            float aar = fmaxf(ax2 - ax1, 0.f) * fmaxf(ay2 - ay1, 0.f);
            if (lane == 0) fstate[bi] = 1;
            __syncthreads();
            for (int e = lane; e < cnt; e += 64) {
                if (fstate[e] == 0) {
                    u64 kv = kb[e];
                    int o2 = (int)(u32)kv;
                    const float* q2 = P + o2 * 6;
                    float bx1 = q2[0], by1 = q2[1], bx2 = q2[2], by2 = q2[3];
                    float br = fmaxf(bx2 - bx1, 0.f) * fmaxf(by2 - by1, 0.f);
                    float ix1 = fmaxf(ax1, bx1), iy1 = fmaxf(ay1, by1);
                    float ix2 = fminf(ax2, bx2), iy2 = fminf(ay2, by2);
                    float inter = fmaxf(ix2 - ix1, 0.f) * fmaxf(iy2 - iy1, 0.f);
                    if (inter / fmaxf(aar + br - inter, 1e-8f) > IOU_T) {
                        fstate[e] = 2;
                        int p = atomicAdd(&supCnt[b], 1);
                        supList[(size_t)b * NB + p] = (u32)o2;
                    }
                }
            }
            if (keptCount > MAX_PER_CLASS && lane == 0) {  // cap: kept in NMS, removed from output
                int p = atomicAdd(&supCnt[b], 1);
                supList[(size_t)b * NB + p] = (u32)orig;
            }
            __syncthreads();
        }
    }
}

// ====================================================================
// K3 (per batch, 256 thr): sup-bitmap from supList, walk sorted keys,
// ballot-compact first 100 kept, write outputs from pred by orig idx.
// ====================================================================
__global__ __launch_bounds__(256) void k3_out(const float* __restrict__ pred,
                                              const u64* __restrict__ keysG,
                                              const u32* __restrict__ supList,
                                              const int* __restrict__ supCnt,
                                              float* __restrict__ out, int B) {
    const int b = blockIdx.x, tid = threadIdx.x;
    const int wave = tid >> 6, lane = tid & 63;
    __shared__ u32 supMask[NB / 32];       // 256 B bitmap over orig idx
    __shared__ u64 keptM[32];
    __shared__ int kcnt[32], kbase[32];

    for (int i = tid; i < NB / 32; i += 256) supMask[i] = 0u;
    __syncthreads();
    int sc = supCnt[b];
    for (int e = tid; e < sc; e += 256) {
        u32 o = supList[(size_t)b * NB + e];
        atomicOr(&supMask[o >> 5], 1u << (o & 31));
    }
    __syncthreads();

    const u64* kg = keysG + (size_t)b * NB;
    const float* P = pred + (size_t)b * NB * 6;

    for (int cc = wave; cc < 32; cc += 4) {
        u64 k = kg[cc * 64 + lane];
        int orig = (int)(u32)k;
        bool kp = ((k >> 32) != 0) && !((supMask[orig >> 5] >> (orig & 31)) & 1u);
        u64 m = __ballot(kp);
        if (lane == 0) { keptM[cc] = m; kcnt[cc] = __popcll(m); }
    }
    __syncthreads();
    if (tid < 32) {
        int s = 0;
        for (int c2 = 0; c2 < tid; ++c2) s += kcnt[c2];
        kbase[tid] = s;
    }
    __syncthreads();

    float* boxes_out   = out + (size_t)b * MAX_DET * 4;
    float* scores_out  = out + (size_t)B * MAX_DET * 4 + (size_t)b * MAX_DET;
    float* classes_out = out + (size_t)B * MAX_DET * 5 + (size_t)b * MAX_DET;
    float* numdet_out  = out + (size_t)B * MAX_DET * 6 + b;

    for (int cc = wave; cc < 32; cc += 4) {
        u64 m = keptM[cc];
        bool kp = (m >> lane) & 1ull;
        int pos = kbase[cc] + __popcll(m & ((1ull << lane) - 1ull));
        if (kp && pos < MAX_DET) {
            u64 k = kg[cc * 64 + lane];
            int orig = (int)(u32)k;
            const float* q = P + orig * 6;
            boxes_out[pos * 4 + 0] = q[0];
            boxes_out[pos * 4 + 1] = q[1];
            boxes_out[pos * 4 + 2] = q[2];
            boxes_out[pos * 4 + 3] = q[3];
            scores_out[pos]  = __uint_as_float((u32)(k >> 32));
            classes_out[pos] = q[4];
        }
    }
    int total = kbase[31] + kcnt[31];
    int nd = total < MAX_DET ? total : MAX_DET;
    for (int p = nd + tid; p < MAX_DET; p += 256) {
        boxes_out[p * 4 + 0] = 0.f;
        boxes_out[p * 4 + 1] = 0.f;
        boxes_out[p * 4 + 2] = 0.f;
        boxes_out[p * 4 + 3] = 0.f;
        scores_out[p]  = 0.f;
        classes_out[p] = 0.f;
    }
    if (tid == 0) *numdet_out = (float)nd;
}

// ====================================================================
// Fallback (round-0 monolithic, validated) if ws is too small.
// ====================================================================
__global__ __launch_bounds__(1024) void nms_fallback(const float* __restrict__ pred,
                                                     float* __restrict__ out, int B) {
    const int b = blockIdx.x, tid = threadIdx.x;
    __shared__ u64 keys[NB];
    __shared__ float bx1[NB], by1[NB], bx2[NB], by2[NB];
    __shared__ int kc[NB];
    __shared__ int cnt[NCLASSES];
    __shared__ int overflow;
    const float* P = pred + (size_t)b * NB * 6;
    for (int i = tid; i < NB; i += 1024) {
        float s = P[i * 6 + 5];
        keys[i] = (s > CONF_T) ? (((u64)__float_as_uint(s) << 32) | (uint32_t)i)
                               : (u64)(uint32_t)i;
    }
    __syncthreads();
    for (int k = 2; k <= NB; k <<= 1)
        for (int j = k >> 1; j > 0; j >>= 1) {
            for (int i = tid; i < NB; i += 1024) {
                int ixj = i ^ j;
                if (ixj > i) {
                    u64 a = keys[i], c = keys[ixj];
                    bool up = ((i & k) == 0);
                    if (up ? (a < c) : (a > c)) { keys[i] = c; keys[ixj] = a; }
                }
            }
            __syncthreads();
        }
    for (int i = tid; i < NB; i += 1024) {
        u64 k = keys[i];
        int orig = (int)(uint32_t)k;
        const float* q = P + orig * 6;
        bx1[i] = q[0]; by1[i] = q[1]; bx2[i] = q[2]; by2[i] = q[3];
        kc[i] = ((k >> 32) != 0) ? (int)q[4] : -1;
    }
    __syncthreads();
    bool dirty = false;
    for (int i = 0; i < NB - 1; ++i) {
        if (i == 0 || dirty) { __syncthreads(); dirty = false; }
        int ci = kc[i];
        if (ci < 0) continue;
        dirty = true;
        float x1i = bx1[i], y1i = by1[i], x2i = bx2[i], y2i = by2[i];
        float ai = fmaxf(x2i - x1i, 0.f) * fmaxf(y2i - y1i, 0.f);
        for (int j = i + 1 + tid; j < NB; j += 1024) {
            if (kc[j] != ci) continue;
            float ix1 = fmaxf(x1i, bx1[j]), iy1 = fmaxf(y1i, by1[j]);
            float ix2 = fminf(x2i, bx2[j]), iy2 = fminf(y2i, by2[j]);
            float inter = fmaxf(ix2 - ix1, 0.f) * fmaxf(iy2 - iy1, 0.f);
            float aj = fmaxf(bx2[j] - bx1[j], 0.f) * fmaxf(by2[j] - by1[j], 0.f);
            if (inter / fmaxf(ai + aj - inter, 1e-8f) > IOU_T) kc[j] = -1;
        }
    }
    __syncthreads();
    for (int i = tid; i < NCLASSES; i += 1024) cnt[i] = 0;
    if (tid == 0) overflow = 0;
    __syncthreads();
    for (int i = tid; i < NB; i += 1024) if (kc[i] >= 0) atomicAdd(&cnt[kc[i]], 1);
    __syncthreads();
    if (tid < NCLASSES && cnt[tid] > MAX_PER_CLASS) atomicOr(&overflow, 1);
    __syncthreads();
    if (overflow) {
        if (tid == 0) {
            for (int c = 0; c < NCLASSES; ++c) cnt[c] = 0;
            for (int i = 0; i < NB; ++i)
                if (kc[i] >= 0 && ++cnt[kc[i]] > MAX_PER_CLASS) kc[i] = -1;
        }
        __syncthreads();
    }
    if (tid < 64) {
        const int lane = tid;
        float* boxes_out   = out + (size_t)b * MAX_DET * 4;
        float* scores_out  = out + (size_t)B * MAX_DET * 4 + (size_t)b * MAX_DET;
        float* classes_out = out + (size_t)B * MAX_DET * 5 + (size_t)b * MAX_DET;
        float* numdet_out  = out + (size_t)B * MAX_DET * 6 + b;
        int running = 0;
        for (int chunk = 0; chunk < NB / 64; ++chunk) {
            int j = chunk * 64 + lane;
            int c = kc[j];
            bool k = (c >= 0);
            u64 m = __ballot(k);
            int pos = running + __popcll(m & ((1ull << lane) - 1ull));
            if (k && pos < MAX_DET) {
                boxes_out[pos * 4 + 0] = bx1[j];
                boxes_out[pos * 4 + 1] = by1[j];
                boxes_out[pos * 4 + 2] = bx2[j];
                boxes_out[pos * 4 + 3] = by2[j];
                scores_out[pos]  = __uint_as_float((uint32_t)(keys[j] >> 32));
                classes_out[pos] = (float)c;
            }
            running += __popcll(m);
        }
        int nd = running < MAX_DET ? running : MAX_DET;
        for (int p = nd + lane; p < MAX_DET; p += 64) {
            boxes_out[p * 4 + 0] = 0.f; boxes_out[p * 4 + 1] = 0.f;
            boxes_out[p * 4 + 2] = 0.f; boxes_out[p * 4 + 3] = 0.f;
            scores_out[p] = 0.f; classes_out[p] = 0.f;
        }
        if (lane == 0) *numdet_out = (float)nd;
    }
}

extern "C" void kernel_launch(void* const* d_in, const int* in_sizes, int n_in,
                              void* d_out, int out_size, void* d_ws, size_t ws_size,
                              hipStream_t stream) {
    const float* pred = (const float*)d_in[0];
    float* out = (float*)d_out;
    const int B = in_sizes[0] / (NB * 6);
    const size_t nBox = (size_t)B * NB;

    char* base = (char*)d_ws;
    u64* keysG   = (u64*)base;   base += nBox * 8;
    u64* keyBuck = (u64*)base;   base += nBox * 8;
    int* clsOffG = (int*)base;   base += (size_t)B * NCLASSES * 4;
    int* clsCntG = (int*)base;   base += (size_t)B * NCLASSES * 4;
    u32* supList = (u32*)base;   base += nBox * 4;
    int* supCnt  = (int*)base;   base += (size_t)B * 4;
    size_t need = (size_t)(base - (char*)d_ws);

    if (ws_size < need) {
        nms_fallback<<<B, 1024, 0, stream>>>(pred, out, B);
        return;
    }

    k1_sort<<<B, 512, 0, stream>>>(pred, keysG, keyBuck, clsOffG, clsCntG, supCnt);
    k2_nms<<<dim3(NCLASSES, B), 64, 0, stream>>>(pred, keyBuck, clsOffG, clsCntG, supList, supCnt);
    k3_out<<<B, 256, 0, stream>>>(pred, keysG, supList, supCnt, out, B);
}